// Round 12
// baseline (398.383 us; speedup 1.0000x reference)
//
#include <hip/hip_runtime.h>

typedef short short8v __attribute__((ext_vector_type(8)));
typedef float floatx4 __attribute__((ext_vector_type(4)));
typedef unsigned short us4 __attribute__((ext_vector_type(4)));
typedef unsigned short us2 __attribute__((ext_vector_type(2)));

#define EMB 1024
#define QKVW 3072
#define SEQ 2048
#define NH 16
#define HD 64
#define TOPK 64
#define QBLK 16
#define CAP 128                      // compact list capacity per row (ties headroom)
#define SROW 2056                    // scores LDS row stride (ushorts)
#define QSCALE 0.18033688f           // 0.125 / ln2 : folded into Q so p = exp2(s' - m')
// scores(code u16) 65792B | hist[16][128] u32 8192B (reused per-row as comp lists) | cnts[16]
#define ATTN_SMEM (QBLK * SROW * 2 + QBLK * CAP * 4 + 64)

#define GLDS16(gp, lp)                                                        \
  __builtin_amdgcn_global_load_lds(                                           \
      (const __attribute__((address_space(1))) void*)(gp),                    \
      (__attribute__((address_space(3))) void*)(lp), 16, 0, 0)

#if __has_builtin(__builtin_amdgcn_exp2f)
#define EXP2F(x) __builtin_amdgcn_exp2f(x)
#else
#define EXP2F(x) exp2f(x)
#endif

static __device__ __forceinline__ unsigned short f2b(float f) {
  union { float f; unsigned u; } in; in.f = f;
  unsigned u = in.u;
  return (unsigned short)((u + 0x7FFFu + ((u >> 16) & 1u)) >> 16);
}
static __device__ __forceinline__ float b2f(unsigned short b) {
  union { unsigned u; float f; } o; o.u = ((unsigned)b) << 16;
  return o.f;
}
// monotone map: bf16 bits -> u16 with integer order == value order
static __device__ __forceinline__ unsigned mmap(unsigned s) {
  return (s & 0x8000u) ? (~s & 0xFFFFu) : (s | 0x8000u);
}
static __device__ __forceinline__ unsigned short munmap(unsigned u) {
  return (u & 0x8000u) ? (unsigned short)(u ^ 0x8000u) : (unsigned short)(~u & 0xFFFFu);
}
// packed monotone map on 2 x u16
static __device__ __forceinline__ unsigned mmap2(unsigned s) {
  const unsigned t = ((s >> 15) & 0x00010001u) * 0x7FFFu;
  return s ^ (0x80008000u | t);
}

// ---------------- LayerNorm: 1 wave per row, no barriers; 16 rows/block ----------------
__global__ __launch_bounds__(1024) void ln_kernel(const float* __restrict__ X,
    const float* __restrict__ gam, const float* __restrict__ bet,
    unsigned short* __restrict__ H) {
  const int tid = threadIdx.x;
  const int w = tid >> 6, l = tid & 63;
  const int row = blockIdx.x * 16 + w;
  const float* xr = &X[(size_t)row * EMB];
  float4 v0 = *(const float4*)&xr[l * 4];
  float4 v1 = *(const float4*)&xr[256 + l * 4];
  float4 v2 = *(const float4*)&xr[512 + l * 4];
  float4 v3 = *(const float4*)&xr[768 + l * 4];
  float s1 = (v0.x + v0.y + v0.z + v0.w) + (v1.x + v1.y + v1.z + v1.w) +
             (v2.x + v2.y + v2.z + v2.w) + (v3.x + v3.y + v3.z + v3.w);
  float s2 = (v0.x * v0.x + v0.y * v0.y + v0.z * v0.z + v0.w * v0.w) +
             (v1.x * v1.x + v1.y * v1.y + v1.z * v1.z + v1.w * v1.w) +
             (v2.x * v2.x + v2.y * v2.y + v2.z * v2.z + v2.w * v2.w) +
             (v3.x * v3.x + v3.y * v3.y + v3.z * v3.z + v3.w * v3.w);
#pragma unroll
  for (int off = 32; off; off >>= 1) { s1 += __shfl_xor(s1, off); s2 += __shfl_xor(s2, off); }
  const float mu = s1 * (1.f / EMB);
  const float var = s2 * (1.f / EMB) - mu * mu;
  const float rs = rsqrtf(var + 1e-5f);
  unsigned short* hr = &H[(size_t)row * EMB];
#pragma unroll
  for (int i = 0; i < 4; ++i) {
    const int c = i * 256 + l * 4;
    const float4 v = (i == 0) ? v0 : ((i == 1) ? v1 : ((i == 2) ? v2 : v3));
    const float4 gv = *(const float4*)&gam[c];
    const float4 bv = *(const float4*)&bet[c];
    us4 o;
    o.x = f2b((v.x - mu) * rs * gv.x + bv.x);
    o.y = f2b((v.y - mu) * rs * gv.y + bv.y);
    o.z = f2b((v.z - mu) * rs * gv.z + bv.z);
    o.w = f2b((v.w - mu) * rs * gv.w + bv.w);
    *(us4*)&hr[c] = o;
  }
}

// ---------------- ALL weight converts + bias pack in ONE launch ----------------
__global__ __launch_bounds__(256) void wcvt_all_kernel(
    const float* __restrict__ Wq, const float* __restrict__ Wk,
    const float* __restrict__ Wv, const float* __restrict__ Wo,
    const float* __restrict__ W1, const float* __restrict__ W2,
    const float* __restrict__ bq, const float* __restrict__ bk,
    const float* __restrict__ bv,
    unsigned short* __restrict__ WqkvT, unsigned short* __restrict__ WoT,
    unsigned short* __restrict__ W1T, unsigned short* __restrict__ W2T,
    float* __restrict__ bqkv) {
  const int bid = blockIdx.x;
  const int tid = threadIdx.x;
  if (bid >= 3072) {  // bias pack
    const int i = (bid - 3072) * 256 + tid;
    float v;
    if (i < 1024) v = bq[i] * QSCALE;
    else if (i < 2048) v = bk[i - 1024];
    else v = bv[i - 2048];
    bqkv[i] = v;
    return;
  }
  const float* W; unsigned short* WT; int K, N, t; float scale = 1.f;
  if (bid < 768) {
    const int seg = bid >> 8; t = bid & 255;
    W = (seg == 0) ? Wq : ((seg == 1) ? Wk : Wv);
    WT = WqkvT + (size_t)seg * 1024 * 1024;
    K = 1024; N = 1024;
    if (seg == 0) scale = QSCALE;
  } else if (bid < 1024) {
    t = bid - 768;  W = Wo; WT = WoT; K = 1024; N = 1024;
  } else if (bid < 2048) {
    t = bid - 1024; W = W1; WT = W1T; K = 1024; N = 4096;
  } else {
    t = bid - 2048; W = W2; WT = W2T; K = 4096; N = 1024;
  }
  const int sh = (N == 4096) ? 6 : 4;        // tiles along n
  const int n0 = (t & ((1 << sh) - 1)) * 64, k0 = (t >> sh) * 64;
  __shared__ unsigned short tl[64][72];
#pragma unroll
  for (int i = 0; i < 4; ++i) {
    const int f = i * 256 + tid;
    const int k = f >> 4, n4 = (f & 15) * 4;
    const float4 v = *(const float4*)&W[(size_t)(k0 + k) * N + n0 + n4];
    tl[n4 + 0][k] = f2b(v.x * scale);
    tl[n4 + 1][k] = f2b(v.y * scale);
    tl[n4 + 2][k] = f2b(v.z * scale);
    tl[n4 + 3][k] = f2b(v.w * scale);
  }
  __syncthreads();
#pragma unroll
  for (int i = 0; i < 2; ++i) {
    const int f = i * 256 + tid;
    const int n = f >> 3, c8 = (f & 7) * 8;
    short8v o;
#pragma unroll
    for (int j = 0; j < 8; ++j) o[j] = (short)tl[n][c8 + j];
    *(short8v*)&WT[(size_t)(n0 + n) * K + k0 + c8] = o;
  }
}

// XCD-aware bijective swizzle of the flattened 2D grid (nwg % 8 == 0 for all launches)
static __device__ __forceinline__ void xcd_tile(int& bm, int& bn, int tn) {
  const int gx = gridDim.x;
  const int nwg = gx * gridDim.y;
  const int flat = blockIdx.y * gx + blockIdx.x;
  const int q8 = nwg >> 3;
  const int wg = (flat & 7) * q8 + (flat >> 3);
  bm = (wg / gx) * 128;
  bn = (wg % gx) * tn;
}

// ---------------- GEMM 4-wave, BK=32, 3-buffer 2-deep prefetch, counted vmcnt ----------------
// Iter t: issue tile t+2 loads (newest 4), compute tile t, s_waitcnt vmcnt(4) (tile t+1
// retired per-wave), s_barrier (all waves' t+1 retired + done reading buf t). Loads for
// t+2 stay in flight ACROSS the barrier — no vmcnt(0) drain in the steady state.
template <int EPI>
__global__ __launch_bounds__(256) void gemm_bt4_kernel(
    const unsigned short* __restrict__ A, const unsigned short* __restrict__ BT,
    const float* __restrict__ bias, const float* __restrict__ res,
    void* __restrict__ Cout, int M, int N, int K) {
  __shared__ __align__(16) unsigned short lA[3][128 * 32];
  __shared__ __align__(16) unsigned short lB[3][128 * 32];
  const int tid = threadIdx.x;
  const int l = tid & 63, w = tid >> 6;
  const int wm = (w >> 1) * 64, wn = (w & 1) * 64;
  int bm, bn; xcd_tile(bm, bn, 128);
  const int g = l >> 4, r16 = l & 15;
  const int lr = l >> 2, lc = (l & 3) * 8;   // 4 lanes/row, 16 rows/issue
  floatx4 acc[4][4] = {};
  const int nt = K >> 5;
#pragma unroll
  for (int j = 0; j < 2; ++j) {              // prologue: tile0 -> buf0
    GLDS16(&A[(size_t)(bm + w * 32 + j * 16 + lr) * K + lc], &lA[0][(w * 32 + j * 16) * 32]);
    GLDS16(&BT[(size_t)(bn + w * 32 + j * 16 + lr) * K + lc], &lB[0][(w * 32 + j * 16) * 32]);
  }
#pragma unroll
  for (int j = 0; j < 2; ++j) {              // tile1 -> buf1
    GLDS16(&A[(size_t)(bm + w * 32 + j * 16 + lr) * K + 32 + lc], &lA[1][(w * 32 + j * 16) * 32]);
    GLDS16(&BT[(size_t)(bn + w * 32 + j * 16 + lr) * K + 32 + lc], &lB[1][(w * 32 + j * 16) * 32]);
  }
  asm volatile("s_waitcnt vmcnt(4)" ::: "memory");   // tile0 retired; tile1 in flight
  __builtin_amdgcn_s_barrier();
  __builtin_amdgcn_sched_barrier(0);
  int b0 = 0, b1 = 1, b2 = 2;
  for (int t = 0; t < nt; ++t) {
    const bool pf = (t + 2 < nt);
    if (pf) {
      const int kt = (t + 2) << 5;
#pragma unroll
      for (int j = 0; j < 2; ++j) {
        GLDS16(&A[(size_t)(bm + w * 32 + j * 16 + lr) * K + kt + lc],
               &lA[b2][(w * 32 + j * 16) * 32]);
        GLDS16(&BT[(size_t)(bn + w * 32 + j * 16 + lr) * K + kt + lc],
               &lB[b2][(w * 32 + j * 16) * 32]);
      }
    }
    short8v a[4], b[4];
#pragma unroll
    for (int m = 0; m < 4; ++m)
      a[m] = *(const short8v*)&lA[b0][(wm + m * 16 + r16) * 32 + g * 8];
#pragma unroll
    for (int n = 0; n < 4; ++n)
      b[n] = *(const short8v*)&lB[b0][(wn + n * 16 + r16) * 32 + g * 8];
#pragma unroll
    for (int m = 0; m < 4; ++m)
#pragma unroll
      for (int n = 0; n < 4; ++n)
        acc[m][n] = __builtin_amdgcn_mfma_f32_16x16x32_bf16(a[m], b[n], acc[m][n], 0, 0, 0);
    if (t + 1 < nt) {
      if (pf) asm volatile("s_waitcnt vmcnt(4)" ::: "memory");
      else    asm volatile("s_waitcnt vmcnt(0)" ::: "memory");
      __builtin_amdgcn_s_barrier();
      __builtin_amdgcn_sched_barrier(0);
    }
    const int tmp = b0; b0 = b1; b1 = b2; b2 = tmp;
  }
#pragma unroll
  for (int m = 0; m < 4; ++m) {
#pragma unroll
    for (int n = 0; n < 4; ++n) {
#pragma unroll
      for (int r = 0; r < 4; ++r) {
        const int gm = bm + wm + m * 16 + g * 4 + r;
        const int gn = bn + wn + n * 16 + r16;
        float v = acc[m][n][r] + bias[gn];
        if constexpr (EPI == 0) {
          ((unsigned short*)Cout)[(size_t)gm * N + gn] = f2b(v);
        } else if constexpr (EPI == 1) {
          const float ge = 0.5f * v * (1.f + erff(v * 0.70710678118f));
          ((unsigned short*)Cout)[(size_t)gm * N + gn] = f2b(ge);
        } else {
          ((float*)Cout)[(size_t)gm * N + gn] = v + res[(size_t)gm * N + gn];
        }
      }
    }
  }
}

// ---------------- GEMM 4-wave, 128x64 tile, same 3-buffer pipeline (Wo, FFN2) ----------------
template <int EPI>
__global__ __launch_bounds__(256) void gemm_n64_kernel(
    const unsigned short* __restrict__ A, const unsigned short* __restrict__ BT,
    const float* __restrict__ bias, const float* __restrict__ res,
    void* __restrict__ Cout, int M, int N, int K) {
  __shared__ __align__(16) unsigned short lA[3][128 * 32];
  __shared__ __align__(16) unsigned short lB[3][64 * 32];
  const int tid = threadIdx.x;
  const int l = tid & 63, w = tid >> 6;
  const int wm = (w & 1) * 64, wn = (w >> 1) * 32;   // 2x2 wave grid over 128x64
  int bm, bn; xcd_tile(bm, bn, 64);
  const int g = l >> 4, r16 = l & 15;
  const int lr = l >> 2, lc = (l & 3) * 8;
  floatx4 acc[4][2] = {};
  const int nt = K >> 5;
#pragma unroll
  for (int j = 0; j < 2; ++j)
    GLDS16(&A[(size_t)(bm + w * 32 + j * 16 + lr) * K + lc], &lA[0][(w * 32 + j * 16) * 32]);
  GLDS16(&BT[(size_t)(bn + w * 16 + lr) * K + lc], &lB[0][(w * 16) * 32]);
#pragma unroll
  for (int j = 0; j < 2; ++j)
    GLDS16(&A[(size_t)(bm + w * 32 + j * 16 + lr) * K + 32 + lc], &lA[1][(w * 32 + j * 16) * 32]);
  GLDS16(&BT[(size_t)(bn + w * 16 + lr) * K + 32 + lc], &lB[1][(w * 16) * 32]);
  asm volatile("s_waitcnt vmcnt(3)" ::: "memory");
  __builtin_amdgcn_s_barrier();
  __builtin_amdgcn_sched_barrier(0);
  int b0 = 0, b1 = 1, b2 = 2;
  for (int t = 0; t < nt; ++t) {
    const bool pf = (t + 2 < nt);
    if (pf) {
      const int kt = (t + 2) << 5;
#pragma unroll
      for (int j = 0; j < 2; ++j)
        GLDS16(&A[(size_t)(bm + w * 32 + j * 16 + lr) * K + kt + lc],
               &lA[b2][(w * 32 + j * 16) * 32]);
      GLDS16(&BT[(size_t)(bn + w * 16 + lr) * K + kt + lc], &lB[b2][(w * 16) * 32]);
    }
    short8v a[4], b[2];
#pragma unroll
    for (int m = 0; m < 4; ++m)
      a[m] = *(const short8v*)&lA[b0][(wm + m * 16 + r16) * 32 + g * 8];
#pragma unroll
    for (int n = 0; n < 2; ++n)
      b[n] = *(const short8v*)&lB[b0][(wn + n * 16 + r16) * 32 + g * 8];
#pragma unroll
    for (int m = 0; m < 4; ++m)
#pragma unroll
      for (int n = 0; n < 2; ++n)
        acc[m][n] = __builtin_amdgcn_mfma_f32_16x16x32_bf16(a[m], b[n], acc[m][n], 0, 0, 0);
    if (t + 1 < nt) {
      if (pf) asm volatile("s_waitcnt vmcnt(3)" ::: "memory");
      else    asm volatile("s_waitcnt vmcnt(0)" ::: "memory");
      __builtin_amdgcn_s_barrier();
      __builtin_amdgcn_sched_barrier(0);
    }
    const int tmp = b0; b0 = b1; b1 = b2; b2 = tmp;
  }
#pragma unroll
  for (int m = 0; m < 4; ++m) {
#pragma unroll
    for (int n = 0; n < 2; ++n) {
#pragma unroll
      for (int r = 0; r < 4; ++r) {
        const int gm = bm + wm + m * 16 + g * 4 + r;
        const int gn = bn + wn + n * 16 + r16;
        float v = acc[m][n][r] + bias[gn];
        if constexpr (EPI == 0) {
          ((unsigned short*)Cout)[(size_t)gm * N + gn] = f2b(v);
        } else if constexpr (EPI == 1) {
          const float ge = 0.5f * v * (1.f + erff(v * 0.70710678118f));
          ((unsigned short*)Cout)[(size_t)gm * N + gn] = f2b(ge);
        } else {
          ((float*)Cout)[(size_t)gm * N + gn] = v + res[(size_t)gm * N + gn];
        }
      }
    }
  }
}

// ---------------- Attention: swapped QK^T(packed codes) -> hist top-64 -> compact -> sparse PV ---
// 1024 threads = 16 waves; wave w owns query row w; scores pre-scaled by 1/(8 ln2).
__global__ __launch_bounds__(1024, 8) void attn_kernel(
    const unsigned short* __restrict__ qkv, unsigned short* __restrict__ O) {
  extern __shared__ unsigned short smem[];
  unsigned short (*scores)[SROW] = (unsigned short(*)[SROW])smem;  // mapped u16 codes
  unsigned* hist = (unsigned*)(smem + QBLK * SROW);   // [16][128]; per-row reused as comp list
  unsigned* cnts = (unsigned*)(smem + QBLK * SROW + 4096);  // [16] kept counters

  const int tid = threadIdx.x;
  const int l = tid & 63, w = tid >> 6;        // 16 waves
  const int g = l >> 4, r16 = l & 15;
  const int qb = blockIdx.x;   // 0..127
  const int h = blockIdx.y;    // 0..15
  const int bz = blockIdx.z;   // 0..1
  const size_t rowbase = (size_t)bz * SEQ;
  const int hcol = h * HD;

  // zero histogram (8 KB) + counters
  ((uint2*)hist)[tid] = uint2{0u, 0u};
  if (tid < 16) cnts[tid] = 0u;

  // ---- QK^T (SWAPPED: mfma(K,Q) -> row=key, col=query): wave w covers keys w*128..+127 ----
  {
    const size_t qrow = (rowbase + qb * QBLK + r16) * QKVW + hcol;
    const short8v qf0 = *(const short8v*)&qkv[qrow + g * 8];
    const short8v qf1 = *(const short8v*)&qkv[qrow + 32 + g * 8];
    const int kbase = w * 128;
#pragma unroll 2
    for (int kti = 0; kti < 8; ++kti) {
      const int key0 = kbase + kti * 16;
      const size_t krow = (rowbase + key0 + r16) * QKVW + 1024 + hcol;
      const short8v kf0 = *(const short8v*)&qkv[krow + g * 8];
      const short8v kf1 = *(const short8v*)&qkv[krow + 32 + g * 8];
      floatx4 acc = {0.f, 0.f, 0.f, 0.f};
      acc = __builtin_amdgcn_mfma_f32_16x16x32_bf16(kf0, qf0, acc, 0, 0, 0);
      acc = __builtin_amdgcn_mfma_f32_16x16x32_bf16(kf1, qf1, acc, 0, 0, 0);
      // lane (g,r16) holds scores for keys key0+g*4..+3 of query r16: pack + map + 8B store
      union { float f; unsigned u; } c0, c1, c2, c3;
      c0.f = acc[0]; c1.f = acc[1]; c2.f = acc[2]; c3.f = acc[3];
      const unsigned p01 = __builtin_amdgcn_perm(c1.u, c0.u, 0x07060302u);
      const unsigned p23 = __builtin_amdgcn_perm(c3.u, c2.u, 0x07060302u);
      uint2 pw; pw.x = mmap2(p01); pw.y = mmap2(p23);
      *(uint2*)&scores[r16][key0 + g * 4] = pw;
    }
  }
  __syncthreads();   // scores ready; hist/cnts zero ordered before atomics

  const int quarter = l >> 4, j16 = l & 15;
  const int q = w;                        // wave w owns row w
  unsigned* srow32 = (unsigned*)&scores[q][0];
  unsigned* comp = &hist[q * CAP];        // wave-private

  // pass A: load packed mapped codes, row max (packed u16 max)
  unsigned ux[16];
  us2 mx2 = {0, 0};
#pragma unroll
  for (int i = 0; i < 16; ++i) {
    const unsigned x = srow32[l + 64 * i];
    ux[i] = x;
    union { unsigned u; us2 v; } c; c.u = x;
    mx2 = __builtin_elementwise_max(mx2, c.v);
  }
  unsigned um = (mx2.x > mx2.y) ? (unsigned)mx2.x : (unsigned)mx2.y;
#pragma unroll
  for (int off = 32; off; off >>= 1) {
    const unsigned o2 = (unsigned)__shfl_xor((int)um, off);
    um = (o2 > um) ? o2 : um;
  }
  const float mf = b2f(munmap(um));

  // pass B: exact histogram of d = um - u (bins 0..255)
#pragma unroll
  for (int i = 0; i < 16; ++i) {
    const unsigned d0 = um - (ux[i] & 0xFFFFu);
    const unsigned d1 = um - (ux[i] >> 16);
    if (d0 < 256u) atomicAdd(&comp[d0 >> 1], 1u << ((d0 & 1u) * 16));
    if (d1 < 256u) atomicAdd(&comp[d1 >> 1], 1u << ((d1 & 1u) * 16));
  }
  asm volatile("s_waitcnt lgkmcnt(0)" ::: "memory");
  // scan: lane l covers bins 4l..4l+3; first d with cum count >= 64
  unsigned ut;
  {
    const unsigned w0 = comp[2 * l], w1 = comp[2 * l + 1];
    const unsigned c0 = w0 & 0xFFFFu, c1 = w0 >> 16, c2 = w1 & 0xFFFFu, c3 = w1 >> 16;
    const unsigned s4 = c0 + c1 + c2 + c3;
    unsigned incl = s4;
#pragma unroll
    for (int off = 1; off < 64; off <<= 1) {
      const unsigned t2 = (unsigned)__shfl_up((int)incl, off);
      if (l >= off) incl += t2;
    }
    const unsigned pre = incl - s4;
    unsigned dc = 0xFFFFFFFFu;
    if      (pre + c0 >= TOPK)           dc = 4 * l;
    else if (pre + c0 + c1 >= TOPK)      dc = 4 * l + 1;
    else if (pre + c0 + c1 + c2 >= TOPK) dc = 4 * l + 2;
    else if (incl >= TOPK)               dc = 4 * l + 3;
#pragma unroll
    for (int off = 32; off; off >>= 1) {
      const unsigned o2 = (unsigned)__shfl_xor((int)dc, off);
      dc = (o2 < dc) ? o2 : dc;
    }
    if (dc != 0xFFFFFFFFu) {
      ut = um - dc;
    } else {  // cold exact fallback (rank-64 further than 255 codes below max)
      unsigned t = 0;
#pragma unroll 1
      for (int bit = 15; bit >= 0; --bit) {
        const unsigned cand = t | (1u << bit);
        int c = 0;
#pragma unroll
        for (int i = 0; i < 16; ++i) {
          c += __popcll(__ballot((ux[i] & 0xFFFFu) >= cand));
          c += __popcll(__ballot((ux[i] >> 16) >= cand));
        }
        if (c >= TOPK) t = cand;
      }
      ut = t;
    }
  }

  // phase 1: compaction of kept (key<<16 | code) via per-row LDS atomic counter
#pragma unroll
  for (int i = 0; i < 16; ++i) {
    const unsigned u0 = ux[i] & 0xFFFFu, u1 = ux[i] >> 16;
    const unsigned key0 = 2 * (l + 64 * i);
    if (u0 >= ut) {
      const unsigned pos = atomicAdd(&cnts[q], 1u);
      if (pos < CAP) comp[pos] = (key0 << 16) | u0;
    }
    if (u1 >= ut) {
      const unsigned pos = atomicAdd(&cnts[q], 1u);
      if (pos < CAP) comp[pos] = ((key0 + 1) << 16) | u1;
    }
  }
  asm volatile("s_waitcnt lgkmcnt(0)" ::: "memory");
  unsigned cnt = cnts[q];                 // wave-own row: own atomics complete; broadcast read
  asm volatile("s_waitcnt lgkmcnt(0)" ::: "memory");
  cnt = (cnt < CAP) ? cnt : CAP;          // kept count (>= 64 always)

  // phase 2: exp2 only the compacted entries (<=2 per lane); lsum; write p back
  float e0 = 0.f, e1 = 0.f;
  unsigned c0v = 0, c1v = 0;
  const bool h0 = ((unsigned)l < cnt), h1 = ((unsigned)(l + 64) < cnt);
  if (h0) {
    c0v = comp[l];
    e0 = EXP2F(b2f(munmap(c0v & 0xFFFFu)) - mf);
  }
  if (h1) {
    c1v = comp[l + 64];
    e1 = EXP2F(b2f(munmap(c1v & 0xFFFFu)) - mf);
  }
  float lsum = e0 + e1;
#pragma unroll
  for (int off = 32; off; off >>= 1) lsum += __shfl_xor(lsum, off);
  const float rinv = 1.f / lsum;
  if (h0) {
    unsigned pp; asm("v_cvt_pk_bf16_f32 %0, %1, %2" : "=v"(pp) : "v"(e0), "v"(e0));
    comp[l] = (c0v & 0xFFFF0000u) | (pp & 0xFFFFu);
  }
  if (h1) {
    unsigned pp; asm("v_cvt_pk_bf16_f32 %0, %1, %2" : "=v"(pp) : "v"(e1), "v"(e1));
    comp[l + 64] = (c1v & 0xFFFF0000u) | (pp & 0xFFFFu);
  }

  // ---- sparse PV: 4 keys/iter (one per quarter-wave); lane covers dims 4*j16..+3 ----
  const unsigned short* vbase = &qkv[rowbase * QKVW + 2048 + hcol + j16 * 4];
  float a0 = 0.f, a1 = 0.f, a2 = 0.f, a3 = 0.f;
#pragma unroll 4
  for (int k = 0; k < 16; ++k) {                    // first 64 kept always valid
    const unsigned c = comp[k * 4 + quarter];
    const float p = b2f((unsigned short)(c & 0xFFFFu));
    const unsigned idx = c >> 16;
    const uint2 vv = *(const uint2*)&vbase[(size_t)idx * QKVW];
    union { unsigned u; float f; } t0, t1, t2, t3;
    t0.u = vv.x << 16; t1.u = vv.x & 0xFFFF0000u;
    t2.u = vv.y << 16; t3.u = vv.y & 0xFFFF0000u;
    a0 += p * t0.f; a1 += p * t1.f; a2 += p * t2.f; a3 += p * t3.f;
  }
#pragma unroll 1
  for (unsigned k = 64; k < cnt; k += 4) {          // rare tie remainder
    const unsigned kk = k + quarter;
    const unsigned c = (kk < cnt) ? comp[kk] : 0u;
    const float p = b2f((unsigned short)(c & 0xFFFFu));
    const unsigned idx = c >> 16;
    const uint2 vv = *(const uint2*)&vbase[(size_t)idx * QKVW];
    union { unsigned u; float f; } t0, t1, t2, t3;
    t0.u = vv.x << 16; t1.u = vv.x & 0xFFFF0000u;
    t2.u = vv.y << 16; t3.u = vv.y & 0xFFFF0000u;
    a0 += p * t0.f; a1 += p * t1.f; a2 += p * t2.f; a3 += p * t3.f;
  }
  a0 += __shfl_xor(a0, 16); a0 += __shfl_xor(a0, 32);
  a1 += __shfl_xor(a1, 16); a1 += __shfl_xor(a1, 32);
  a2 += __shfl_xor(a2, 16); a2 += __shfl_xor(a2, 32);
  a3 += __shfl_xor(a3, 16); a3 += __shfl_xor(a3, 32);
  if (l < 16) {
    unsigned w0, w1;
    const float r0 = a0 * rinv, r1 = a1 * rinv, r2 = a2 * rinv, r3 = a3 * rinv;
    asm("v_cvt_pk_bf16_f32 %0, %1, %2" : "=v"(w0) : "v"(r0), "v"(r1));
    asm("v_cvt_pk_bf16_f32 %0, %1, %2" : "=v"(w1) : "v"(r2), "v"(r3));
    uint2 ow; ow.x = w0; ow.y = w1;
    *(uint2*)&O[(rowbase + qb * QBLK + q) * EMB + hcol + j16 * 4] = ow;
  }
}

extern "C" void kernel_launch(void* const* d_in, const int* in_sizes, int n_in,
                              void* d_out, int out_size, void* d_ws, size_t ws_size,
                              hipStream_t stream) {
  (void)in_sizes; (void)n_in; (void)out_size; (void)ws_size;
  const float* x  = (const float*)d_in[0];
  const float* Wq = (const float*)d_in[1];
  const float* bq = (const float*)d_in[2];
  const float* Wk = (const float*)d_in[3];
  const float* bk = (const float*)d_in[4];
  const float* Wv = (const float*)d_in[5];
  const float* bv = (const float*)d_in[6];
  const float* Wo = (const float*)d_in[7];
  const float* bo = (const float*)d_in[8];
  const float* g1 = (const float*)d_in[9];
  const float* be1 = (const float*)d_in[10];
  const float* g2 = (const float*)d_in[11];
  const float* be2 = (const float*)d_in[12];
  const float* W1 = (const float*)d_in[13];
  const float* b1 = (const float*)d_in[14];
  const float* W2 = (const float*)d_in[15];
  const float* b2 = (const float*)d_in[16];
  float* out = (float*)d_out;

  char* ws = (char*)d_ws;
  float* x1 = (float*)ws;                                            // [0,16) MB fp32
  unsigned short* hbuf  = (unsigned short*)(ws + ((size_t)16 << 20)); // [16,24)
  unsigned short* qkvb  = (unsigned short*)(ws + ((size_t)24 << 20)); // [24,48)
  unsigned short* Ob    = (unsigned short*)(ws + ((size_t)48 << 20)); // [48,56)
  unsigned short* ff1   = (unsigned short*)(ws + ((size_t)24 << 20)); // [24,56) reuses qkv+Ob
  float* bqkv           = (float*)(ws + ((size_t)48 << 20));          // 12KB, dead before Ob
  unsigned short* WqkvT = (unsigned short*)(ws + ((size_t)56 << 20)); // [56,62)
  unsigned short* WoT   = (unsigned short*)(ws + ((size_t)62 << 20)); // [62,64)
  unsigned short* W1T   = (unsigned short*)(ws + ((size_t)64 << 20)); // [64,72)
  unsigned short* W2T   = (unsigned short*)(ws + ((size_t)72 << 20)); // [72,80)

  wcvt_all_kernel<<<dim3(3084), 256, 0, stream>>>(Wq, Wk, Wv, Wo, W1, W2, bq, bk, bv,
                                                  WqkvT, WoT, W1T, W2T, bqkv);

  ln_kernel<<<dim3(256), 1024, 0, stream>>>(x, g1, be1, hbuf);
  gemm_bt4_kernel<0><<<dim3(24, 32), 256, 0, stream>>>(hbuf, WqkvT, bqkv, nullptr, qkvb,
                                                       4096, QKVW, 1024);
  (void)hipFuncSetAttribute((const void*)attn_kernel,
                            hipFuncAttributeMaxDynamicSharedMemorySize, ATTN_SMEM);
  attn_kernel<<<dim3(128, 16, 2), 1024, ATTN_SMEM, stream>>>(qkvb, Ob);
  gemm_n64_kernel<2><<<dim3(16, 32), 256, 0, stream>>>(Ob, WoT, bo, x, x1, 4096, 1024, 1024);
  ln_kernel<<<dim3(256), 1024, 0, stream>>>(x1, g2, be2, hbuf);
  gemm_bt4_kernel<1><<<dim3(32, 32), 256, 0, stream>>>(hbuf, W1T, b1, nullptr, ff1,
                                                       4096, 4096, 1024);
  gemm_n64_kernel<2><<<dim3(16, 32), 256, 0, stream>>>(ff1, W2T, b2, x1, out, 4096, 1024, 4096);
}

// Round 13
// 386.482 us; speedup vs baseline: 1.0308x; 1.0308x over previous
//
#include <hip/hip_runtime.h>

typedef short short8v __attribute__((ext_vector_type(8)));
typedef float floatx4 __attribute__((ext_vector_type(4)));
typedef unsigned short us4 __attribute__((ext_vector_type(4)));
typedef unsigned short us2 __attribute__((ext_vector_type(2)));

#define EMB 1024
#define QKVW 3072
#define SEQ 2048
#define NH 16
#define HD 64
#define TOPK 64
#define QBLK 16
#define CAP 128                      // compact list capacity per row (ties headroom)
#define SROW 2056                    // scores LDS row stride (ushorts)
#define QSCALE 0.18033688f           // 0.125 / ln2 : folded into Q so p = exp2(s' - m')
// scores(code u16) 65792B | hist[16][128] u32 8192B (reused per-row as comp lists)
#define ATTN_SMEM (QBLK * SROW * 2 + QBLK * CAP * 4)

#define GLDS16(gp, lp)                                                        \
  __builtin_amdgcn_global_load_lds(                                           \
      (const __attribute__((address_space(1))) void*)(gp),                    \
      (__attribute__((address_space(3))) void*)(lp), 16, 0, 0)

#if __has_builtin(__builtin_amdgcn_exp2f)
#define EXP2F(x) __builtin_amdgcn_exp2f(x)
#else
#define EXP2F(x) exp2f(x)
#endif

static __device__ __forceinline__ unsigned short f2b(float f) {
  union { float f; unsigned u; } in; in.f = f;
  unsigned u = in.u;
  return (unsigned short)((u + 0x7FFFu + ((u >> 16) & 1u)) >> 16);
}
static __device__ __forceinline__ float b2f(unsigned short b) {
  union { unsigned u; float f; } o; o.u = ((unsigned)b) << 16;
  return o.f;
}
// monotone map: bf16 bits -> u16 with integer order == value order
static __device__ __forceinline__ unsigned mmap(unsigned s) {
  return (s & 0x8000u) ? (~s & 0xFFFFu) : (s | 0x8000u);
}
static __device__ __forceinline__ unsigned short munmap(unsigned u) {
  return (u & 0x8000u) ? (unsigned short)(u ^ 0x8000u) : (unsigned short)(~u & 0xFFFFu);
}
// packed monotone map on 2 x u16
static __device__ __forceinline__ unsigned mmap2(unsigned s) {
  const unsigned t = ((s >> 15) & 0x00010001u) * 0x7FFFu;
  return s ^ (0x80008000u | t);
}

// ---------------- LayerNorm body: one wave normalizes one row (no barriers, no LDS) --------
static __device__ __forceinline__ void ln_row(const float* __restrict__ X,
    const float* __restrict__ gam, const float* __restrict__ bet,
    unsigned short* __restrict__ H, int row, int l) {
  const float* xr = &X[(size_t)row * EMB];
  float4 v0 = *(const float4*)&xr[l * 4];
  float4 v1 = *(const float4*)&xr[256 + l * 4];
  float4 v2 = *(const float4*)&xr[512 + l * 4];
  float4 v3 = *(const float4*)&xr[768 + l * 4];
  float s1 = (v0.x + v0.y + v0.z + v0.w) + (v1.x + v1.y + v1.z + v1.w) +
             (v2.x + v2.y + v2.z + v2.w) + (v3.x + v3.y + v3.z + v3.w);
  float s2 = (v0.x * v0.x + v0.y * v0.y + v0.z * v0.z + v0.w * v0.w) +
             (v1.x * v1.x + v1.y * v1.y + v1.z * v1.z + v1.w * v1.w) +
             (v2.x * v2.x + v2.y * v2.y + v2.z * v2.z + v2.w * v2.w) +
             (v3.x * v3.x + v3.y * v3.y + v3.z * v3.z + v3.w * v3.w);
#pragma unroll
  for (int off = 32; off; off >>= 1) { s1 += __shfl_xor(s1, off); s2 += __shfl_xor(s2, off); }
  const float mu = s1 * (1.f / EMB);
  const float var = s2 * (1.f / EMB) - mu * mu;
  const float rs = rsqrtf(var + 1e-5f);
  unsigned short* hr = &H[(size_t)row * EMB];
#pragma unroll
  for (int i = 0; i < 4; ++i) {
    const int c = i * 256 + l * 4;
    const float4 v = (i == 0) ? v0 : ((i == 1) ? v1 : ((i == 2) ? v2 : v3));
    const float4 gv = *(const float4*)&gam[c];
    const float4 bv = *(const float4*)&bet[c];
    us4 o;
    o.x = f2b((v.x - mu) * rs * gv.x + bv.x);
    o.y = f2b((v.y - mu) * rs * gv.y + bv.y);
    o.z = f2b((v.z - mu) * rs * gv.z + bv.z);
    o.w = f2b((v.w - mu) * rs * gv.w + bv.w);
    *(us4*)&hr[c] = o;
  }
}

// ---------------- LayerNorm standalone (ln2): 4 rows/block, 256 thr ----------------
__global__ __launch_bounds__(256) void ln_kernel(const float* __restrict__ X,
    const float* __restrict__ gam, const float* __restrict__ bet,
    unsigned short* __restrict__ H) {
  const int w = threadIdx.x >> 6, l = threadIdx.x & 63;
  ln_row(X, gam, bet, H, blockIdx.x * 4 + w, l);
}

// ---------------- ALL weight converts + bias pack + LN1 in ONE launch ----------------
// blocks 0..3071: weight tiles; 3072..3083: bias pack; 3084..4107: LN1 (4 rows each).
__global__ __launch_bounds__(256) void wcvt_all_kernel(
    const float* __restrict__ Wq, const float* __restrict__ Wk,
    const float* __restrict__ Wv, const float* __restrict__ Wo,
    const float* __restrict__ W1, const float* __restrict__ W2,
    const float* __restrict__ bq, const float* __restrict__ bk,
    const float* __restrict__ bv,
    unsigned short* __restrict__ WqkvT, unsigned short* __restrict__ WoT,
    unsigned short* __restrict__ W1T, unsigned short* __restrict__ W2T,
    float* __restrict__ bqkv,
    const float* __restrict__ x, const float* __restrict__ g1,
    const float* __restrict__ be1, unsigned short* __restrict__ hbuf) {
  const int bid = blockIdx.x;
  const int tid = threadIdx.x;
  if (bid >= 3084) {  // LN1: 4 rows per block
    const int w = tid >> 6, l = tid & 63;
    ln_row(x, g1, be1, hbuf, (bid - 3084) * 4 + w, l);
    return;
  }
  if (bid >= 3072) {  // bias pack
    const int i = (bid - 3072) * 256 + tid;
    float v;
    if (i < 1024) v = bq[i] * QSCALE;
    else if (i < 2048) v = bk[i - 1024];
    else v = bv[i - 2048];
    bqkv[i] = v;
    return;
  }
  const float* W; unsigned short* WT; int K, N, t; float scale = 1.f;
  if (bid < 768) {
    const int seg = bid >> 8; t = bid & 255;
    W = (seg == 0) ? Wq : ((seg == 1) ? Wk : Wv);
    WT = WqkvT + (size_t)seg * 1024 * 1024;
    K = 1024; N = 1024;
    if (seg == 0) scale = QSCALE;
  } else if (bid < 1024) {
    t = bid - 768;  W = Wo; WT = WoT; K = 1024; N = 1024;
  } else if (bid < 2048) {
    t = bid - 1024; W = W1; WT = W1T; K = 1024; N = 4096;
  } else {
    t = bid - 2048; W = W2; WT = W2T; K = 4096; N = 1024;
  }
  const int sh = (N == 4096) ? 6 : 4;        // tiles along n
  const int n0 = (t & ((1 << sh) - 1)) * 64, k0 = (t >> sh) * 64;
  __shared__ unsigned short tl[64][72];
#pragma unroll
  for (int i = 0; i < 4; ++i) {
    const int f = i * 256 + tid;
    const int k = f >> 4, n4 = (f & 15) * 4;
    const float4 v = *(const float4*)&W[(size_t)(k0 + k) * N + n0 + n4];
    tl[n4 + 0][k] = f2b(v.x * scale);
    tl[n4 + 1][k] = f2b(v.y * scale);
    tl[n4 + 2][k] = f2b(v.z * scale);
    tl[n4 + 3][k] = f2b(v.w * scale);
  }
  __syncthreads();
#pragma unroll
  for (int i = 0; i < 2; ++i) {
    const int f = i * 256 + tid;
    const int n = f >> 3, c8 = (f & 7) * 8;
    short8v o;
#pragma unroll
    for (int j = 0; j < 8; ++j) o[j] = (short)tl[n][c8 + j];
    *(short8v*)&WT[(size_t)(n0 + n) * K + k0 + c8] = o;
  }
}

// XCD-aware bijective swizzle of the flattened 2D grid (nwg % 8 == 0 for all launches)
static __device__ __forceinline__ void xcd_tile(int& bm, int& bn, int tn) {
  const int gx = gridDim.x;
  const int nwg = gx * gridDim.y;
  const int flat = blockIdx.y * gx + blockIdx.x;
  const int q8 = nwg >> 3;
  const int wg = (flat & 7) * q8 + (flat >> 3);
  bm = (wg / gx) * 128;
  bn = (wg % gx) * tn;
}

// ---------------- GEMM 4-wave, BK=32, double-buffered 2-phase pipeline (R10 best) ----------
template <int EPI>
__global__ __launch_bounds__(256) void gemm_bt4_kernel(
    const unsigned short* __restrict__ A, const unsigned short* __restrict__ BT,
    const float* __restrict__ bias, const float* __restrict__ res,
    void* __restrict__ Cout, int M, int N, int K) {
  __shared__ __align__(16) unsigned short lA[2][128 * 32];
  __shared__ __align__(16) unsigned short lB[2][128 * 32];
  const int tid = threadIdx.x;
  const int l = tid & 63, w = tid >> 6;
  const int wm = (w >> 1) * 64, wn = (w & 1) * 64;
  int bm, bn; xcd_tile(bm, bn, 128);
  const int g = l >> 4, r16 = l & 15;
  const int lr = l >> 2, lc = (l & 3) * 8;   // 4 lanes/row, 16 rows/issue
  floatx4 acc[4][4] = {};
  const int nt = K >> 5;
#pragma unroll
  for (int j = 0; j < 2; ++j) {              // prologue: stage tile 0 into buf 0
    GLDS16(&A[(size_t)(bm + w * 32 + j * 16 + lr) * K + lc], &lA[0][(w * 32 + j * 16) * 32]);
    GLDS16(&BT[(size_t)(bn + w * 32 + j * 16 + lr) * K + lc], &lB[0][(w * 32 + j * 16) * 32]);
  }
  __syncthreads();
  int cur = 0;
  for (int t = 0; t < nt; ++t) {
    if (t + 1 < nt) {                        // async prefetch next tile into other buffer
      const int kt = (t + 1) << 5;
#pragma unroll
      for (int j = 0; j < 2; ++j) {
        GLDS16(&A[(size_t)(bm + w * 32 + j * 16 + lr) * K + kt + lc],
               &lA[cur ^ 1][(w * 32 + j * 16) * 32]);
        GLDS16(&BT[(size_t)(bn + w * 32 + j * 16 + lr) * K + kt + lc],
               &lB[cur ^ 1][(w * 32 + j * 16) * 32]);
      }
    }
    short8v a[4], b[4];
#pragma unroll
    for (int m = 0; m < 4; ++m)
      a[m] = *(const short8v*)&lA[cur][(wm + m * 16 + r16) * 32 + g * 8];
#pragma unroll
    for (int n = 0; n < 4; ++n)
      b[n] = *(const short8v*)&lB[cur][(wn + n * 16 + r16) * 32 + g * 8];
#pragma unroll
    for (int m = 0; m < 4; ++m)
#pragma unroll
      for (int n = 0; n < 4; ++n)
        acc[m][n] = __builtin_amdgcn_mfma_f32_16x16x32_bf16(a[m], b[n], acc[m][n], 0, 0, 0);
    __syncthreads();                          // drains vm+lgkm: next buf ready, cur buf free
    cur ^= 1;
  }
#pragma unroll
  for (int m = 0; m < 4; ++m) {
#pragma unroll
    for (int n = 0; n < 4; ++n) {
#pragma unroll
      for (int r = 0; r < 4; ++r) {
        const int gm = bm + wm + m * 16 + g * 4 + r;
        const int gn = bn + wn + n * 16 + r16;
        float v = acc[m][n][r] + bias[gn];
        if constexpr (EPI == 0) {
          ((unsigned short*)Cout)[(size_t)gm * N + gn] = f2b(v);
        } else if constexpr (EPI == 1) {
          const float ge = 0.5f * v * (1.f + erff(v * 0.70710678118f));
          ((unsigned short*)Cout)[(size_t)gm * N + gn] = f2b(ge);
        } else {
          ((float*)Cout)[(size_t)gm * N + gn] = v + res[(size_t)gm * N + gn];
        }
      }
    }
  }
}

// ---------------- GEMM 4-wave, 128x64 tile, dbuf 2-phase: for N=1024 (Wo, FFN2) ----------------
template <int EPI>
__global__ __launch_bounds__(256) void gemm_n64_kernel(
    const unsigned short* __restrict__ A, const unsigned short* __restrict__ BT,
    const float* __restrict__ bias, const float* __restrict__ res,
    void* __restrict__ Cout, int M, int N, int K) {
  __shared__ __align__(16) unsigned short lA[2][128 * 32];
  __shared__ __align__(16) unsigned short lB[2][64 * 32];
  const int tid = threadIdx.x;
  const int l = tid & 63, w = tid >> 6;
  const int wm = (w & 1) * 64, wn = (w >> 1) * 32;   // 2x2 wave grid over 128x64
  int bm, bn; xcd_tile(bm, bn, 64);
  const int g = l >> 4, r16 = l & 15;
  const int lr = l >> 2, lc = (l & 3) * 8;
  floatx4 acc[4][2] = {};
  const int nt = K >> 5;
#pragma unroll
  for (int j = 0; j < 2; ++j)
    GLDS16(&A[(size_t)(bm + w * 32 + j * 16 + lr) * K + lc], &lA[0][(w * 32 + j * 16) * 32]);
  GLDS16(&BT[(size_t)(bn + w * 16 + lr) * K + lc], &lB[0][(w * 16) * 32]);
  __syncthreads();
  int cur = 0;
  for (int t = 0; t < nt; ++t) {
    if (t + 1 < nt) {
      const int kt = (t + 1) << 5;
#pragma unroll
      for (int j = 0; j < 2; ++j)
        GLDS16(&A[(size_t)(bm + w * 32 + j * 16 + lr) * K + kt + lc],
               &lA[cur ^ 1][(w * 32 + j * 16) * 32]);
      GLDS16(&BT[(size_t)(bn + w * 16 + lr) * K + kt + lc], &lB[cur ^ 1][(w * 16) * 32]);
    }
    short8v a[4], b[2];
#pragma unroll
    for (int m = 0; m < 4; ++m)
      a[m] = *(const short8v*)&lA[cur][(wm + m * 16 + r16) * 32 + g * 8];
#pragma unroll
    for (int n = 0; n < 2; ++n)
      b[n] = *(const short8v*)&lB[cur][(wn + n * 16 + r16) * 32 + g * 8];
#pragma unroll
    for (int m = 0; m < 4; ++m)
#pragma unroll
      for (int n = 0; n < 2; ++n)
        acc[m][n] = __builtin_amdgcn_mfma_f32_16x16x32_bf16(a[m], b[n], acc[m][n], 0, 0, 0);
    __syncthreads();
    cur ^= 1;
  }
#pragma unroll
  for (int m = 0; m < 4; ++m) {
#pragma unroll
    for (int n = 0; n < 2; ++n) {
#pragma unroll
      for (int r = 0; r < 4; ++r) {
        const int gm = bm + wm + m * 16 + g * 4 + r;
        const int gn = bn + wn + n * 16 + r16;
        float v = acc[m][n][r] + bias[gn];
        if constexpr (EPI == 0) {
          ((unsigned short*)Cout)[(size_t)gm * N + gn] = f2b(v);
        } else if constexpr (EPI == 1) {
          const float ge = 0.5f * v * (1.f + erff(v * 0.70710678118f));
          ((unsigned short*)Cout)[(size_t)gm * N + gn] = f2b(ge);
        } else {
          ((float*)Cout)[(size_t)gm * N + gn] = v + res[(size_t)gm * N + gn];
        }
      }
    }
  }
}

// ---------------- Attention: swapped QK^T(packed codes) -> hist top-64 -> compact -> sparse PV ---
// 1024 threads = 16 waves; wave w owns query row w; scores pre-scaled by 1/(8 ln2).
__global__ __launch_bounds__(1024, 8) void attn_kernel(
    const unsigned short* __restrict__ qkv, unsigned short* __restrict__ O) {
  extern __shared__ unsigned short smem[];
  unsigned short (*scores)[SROW] = (unsigned short(*)[SROW])smem;  // mapped u16 codes
  unsigned* hist = (unsigned*)(smem + QBLK * SROW);  // [16][128]; per-row reused as comp list

  const int tid = threadIdx.x;
  const int l = tid & 63, w = tid >> 6;        // 16 waves
  const int g = l >> 4, r16 = l & 15;
  const int qb = blockIdx.x;   // 0..127
  const int h = blockIdx.y;    // 0..15
  const int bz = blockIdx.z;   // 0..1
  const size_t rowbase = (size_t)bz * SEQ;
  const int hcol = h * HD;

  // zero histogram (8 KB): 1024 threads x 8B
  ((uint2*)hist)[tid] = uint2{0u, 0u};

  // ---- QK^T (SWAPPED: mfma(K,Q) -> row=key, col=query): wave w covers keys w*128..+127 ----
  {
    const size_t qrow = (rowbase + qb * QBLK + r16) * QKVW + hcol;
    const short8v qf0 = *(const short8v*)&qkv[qrow + g * 8];
    const short8v qf1 = *(const short8v*)&qkv[qrow + 32 + g * 8];
    const int kbase = w * 128;
#pragma unroll 2
    for (int kti = 0; kti < 8; ++kti) {
      const int key0 = kbase + kti * 16;
      const size_t krow = (rowbase + key0 + r16) * QKVW + 1024 + hcol;
      const short8v kf0 = *(const short8v*)&qkv[krow + g * 8];
      const short8v kf1 = *(const short8v*)&qkv[krow + 32 + g * 8];
      floatx4 acc = {0.f, 0.f, 0.f, 0.f};
      acc = __builtin_amdgcn_mfma_f32_16x16x32_bf16(kf0, qf0, acc, 0, 0, 0);
      acc = __builtin_amdgcn_mfma_f32_16x16x32_bf16(kf1, qf1, acc, 0, 0, 0);
      // lane (g,r16) holds scores for keys key0+g*4..+3 of query r16: pack + map + 8B store
      union { float f; unsigned u; } c0, c1, c2, c3;
      c0.f = acc[0]; c1.f = acc[1]; c2.f = acc[2]; c3.f = acc[3];
      const unsigned p01 = __builtin_amdgcn_perm(c1.u, c0.u, 0x07060302u);
      const unsigned p23 = __builtin_amdgcn_perm(c3.u, c2.u, 0x07060302u);
      uint2 pw; pw.x = mmap2(p01); pw.y = mmap2(p23);
      *(uint2*)&scores[r16][key0 + g * 4] = pw;
    }
  }
  __syncthreads();   // scores ready; hist zero ordered before atomics

  const unsigned long long ltmask = (1ull << l) - 1ull;
  const int quarter = l >> 4, j16 = l & 15;
  const int q = w;                        // wave w owns row w
  unsigned* srow32 = (unsigned*)&scores[q][0];
  unsigned* comp = &hist[q * CAP];        // wave-private

  // pass A: load packed mapped codes, row max (packed u16 max)
  unsigned ux[16];
  us2 mx2 = {0, 0};
#pragma unroll
  for (int i = 0; i < 16; ++i) {
    const unsigned x = srow32[l + 64 * i];
    ux[i] = x;
    union { unsigned u; us2 v; } c; c.u = x;
    mx2 = __builtin_elementwise_max(mx2, c.v);
  }
  unsigned um = (mx2.x > mx2.y) ? (unsigned)mx2.x : (unsigned)mx2.y;
#pragma unroll
  for (int off = 32; off; off >>= 1) {
    const unsigned o2 = (unsigned)__shfl_xor((int)um, off);
    um = (o2 > um) ? o2 : um;
  }
  const float mf = b2f(munmap(um));

  // pass B: exact histogram of d = um - u (bins 0..255)
#pragma unroll
  for (int i = 0; i < 16; ++i) {
    const unsigned d0 = um - (ux[i] & 0xFFFFu);
    const unsigned d1 = um - (ux[i] >> 16);
    if (d0 < 256u) atomicAdd(&comp[d0 >> 1], 1u << ((d0 & 1u) * 16));
    if (d1 < 256u) atomicAdd(&comp[d1 >> 1], 1u << ((d1 & 1u) * 16));
  }
  asm volatile("s_waitcnt lgkmcnt(0)" ::: "memory");
  // scan: lane l covers bins 4l..4l+3; first d with cum count >= 64
  unsigned ut;
  {
    const unsigned w0 = comp[2 * l], w1 = comp[2 * l + 1];
    const unsigned c0 = w0 & 0xFFFFu, c1 = w0 >> 16, c2 = w1 & 0xFFFFu, c3 = w1 >> 16;
    const unsigned s4 = c0 + c1 + c2 + c3;
    unsigned incl = s4;
#pragma unroll
    for (int off = 1; off < 64; off <<= 1) {
      const unsigned t2 = (unsigned)__shfl_up((int)incl, off);
      if (l >= off) incl += t2;
    }
    const unsigned pre = incl - s4;
    unsigned dc = 0xFFFFFFFFu;
    if      (pre + c0 >= TOPK)           dc = 4 * l;
    else if (pre + c0 + c1 >= TOPK)      dc = 4 * l + 1;
    else if (pre + c0 + c1 + c2 >= TOPK) dc = 4 * l + 2;
    else if (incl >= TOPK)               dc = 4 * l + 3;
#pragma unroll
    for (int off = 32; off; off >>= 1) {
      const unsigned o2 = (unsigned)__shfl_xor((int)dc, off);
      dc = (o2 < dc) ? o2 : dc;
    }
    if (dc != 0xFFFFFFFFu) {
      ut = um - dc;
    } else {  // cold exact fallback (rank-64 further than 255 codes below max)
      unsigned t = 0;
#pragma unroll 1
      for (int bit = 15; bit >= 0; --bit) {
        const unsigned cand = t | (1u << bit);
        int c = 0;
#pragma unroll
        for (int i = 0; i < 16; ++i) {
          c += __popcll(__ballot((ux[i] & 0xFFFFu) >= cand));
          c += __popcll(__ballot((ux[i] >> 16) >= cand));
        }
        if (c >= TOPK) t = cand;
      }
      ut = t;
    }
  }

  // phase 1: ballot-compaction of kept (key<<16 | code) — no exp yet
  unsigned base = 0;
#pragma unroll
  for (int i = 0; i < 16; ++i) {
    const unsigned u0 = ux[i] & 0xFFFFu, u1 = ux[i] >> 16;
    const bool k0 = (u0 >= ut), k1 = (u1 >= ut);
    const unsigned key0 = 2 * (l + 64 * i);
    const unsigned long long m0 = __ballot(k0);
    if (k0) {
      const unsigned pos = base + (unsigned)__popcll(m0 & ltmask);
      if (pos < CAP) comp[pos] = (key0 << 16) | u0;
    }
    base += (unsigned)__popcll(m0);
    const unsigned long long m1 = __ballot(k1);
    if (k1) {
      const unsigned pos = base + (unsigned)__popcll(m1 & ltmask);
      if (pos < CAP) comp[pos] = ((key0 + 1) << 16) | u1;
    }
    base += (unsigned)__popcll(m1);
  }
  const unsigned cnt = (base < CAP) ? base : CAP;   // kept count (>= 64 always)

  // phase 2: exp2 only the compacted entries (<=2 per lane); lsum; write p back
  float e0 = 0.f, e1 = 0.f;
  unsigned c0v = 0, c1v = 0;
  const bool h0 = ((unsigned)l < cnt), h1 = ((unsigned)(l + 64) < cnt);
  if (h0) {
    c0v = comp[l];
    e0 = EXP2F(b2f(munmap(c0v & 0xFFFFu)) - mf);
  }
  if (h1) {
    c1v = comp[l + 64];
    e1 = EXP2F(b2f(munmap(c1v & 0xFFFFu)) - mf);
  }
  float lsum = e0 + e1;
#pragma unroll
  for (int off = 32; off; off >>= 1) lsum += __shfl_xor(lsum, off);
  const float rinv = 1.f / lsum;
  if (h0) {
    unsigned pp; asm("v_cvt_pk_bf16_f32 %0, %1, %2" : "=v"(pp) : "v"(e0), "v"(e0));
    comp[l] = (c0v & 0xFFFF0000u) | (pp & 0xFFFFu);
  }
  if (h1) {
    unsigned pp; asm("v_cvt_pk_bf16_f32 %0, %1, %2" : "=v"(pp) : "v"(e1), "v"(e1));
    comp[l + 64] = (c1v & 0xFFFF0000u) | (pp & 0xFFFFu);
  }

  // ---- sparse PV: 4 keys/iter (one per quarter-wave); lane covers dims 4*j16..+3 ----
  const unsigned short* vbase = &qkv[rowbase * QKVW + 2048 + hcol + j16 * 4];
  float a0 = 0.f, a1 = 0.f, a2 = 0.f, a3 = 0.f;
#pragma unroll 4
  for (int k = 0; k < 16; ++k) {                    // first 64 kept always valid
    const unsigned c = comp[k * 4 + quarter];
    const float p = b2f((unsigned short)(c & 0xFFFFu));
    const unsigned idx = c >> 16;
    const uint2 vv = *(const uint2*)&vbase[(size_t)idx * QKVW];
    union { unsigned u; float f; } t0, t1, t2, t3;
    t0.u = vv.x << 16; t1.u = vv.x & 0xFFFF0000u;
    t2.u = vv.y << 16; t3.u = vv.y & 0xFFFF0000u;
    a0 += p * t0.f; a1 += p * t1.f; a2 += p * t2.f; a3 += p * t3.f;
  }
#pragma unroll 1
  for (unsigned k = 64; k < cnt; k += 4) {          // rare tie remainder
    const unsigned kk = k + quarter;
    const unsigned c = (kk < cnt) ? comp[kk] : 0u;
    const float p = b2f((unsigned short)(c & 0xFFFFu));
    const unsigned idx = c >> 16;
    const uint2 vv = *(const uint2*)&vbase[(size_t)idx * QKVW];
    union { unsigned u; float f; } t0, t1, t2, t3;
    t0.u = vv.x << 16; t1.u = vv.x & 0xFFFF0000u;
    t2.u = vv.y << 16; t3.u = vv.y & 0xFFFF0000u;
    a0 += p * t0.f; a1 += p * t1.f; a2 += p * t2.f; a3 += p * t3.f;
  }
  a0 += __shfl_xor(a0, 16); a0 += __shfl_xor(a0, 32);
  a1 += __shfl_xor(a1, 16); a1 += __shfl_xor(a1, 32);
  a2 += __shfl_xor(a2, 16); a2 += __shfl_xor(a2, 32);
  a3 += __shfl_xor(a3, 16); a3 += __shfl_xor(a3, 32);
  if (l < 16) {
    unsigned w0, w1;
    const float r0 = a0 * rinv, r1 = a1 * rinv, r2 = a2 * rinv, r3 = a3 * rinv;
    asm("v_cvt_pk_bf16_f32 %0, %1, %2" : "=v"(w0) : "v"(r0), "v"(r1));
    asm("v_cvt_pk_bf16_f32 %0, %1, %2" : "=v"(w1) : "v"(r2), "v"(r3));
    uint2 ow; ow.x = w0; ow.y = w1;
    *(uint2*)&O[(rowbase + qb * QBLK + q) * EMB + hcol + j16 * 4] = ow;
  }
}

extern "C" void kernel_launch(void* const* d_in, const int* in_sizes, int n_in,
                              void* d_out, int out_size, void* d_ws, size_t ws_size,
                              hipStream_t stream) {
  (void)in_sizes; (void)n_in; (void)out_size; (void)ws_size;
  const float* x  = (const float*)d_in[0];
  const float* Wq = (const float*)d_in[1];
  const float* bq = (const float*)d_in[2];
  const float* Wk = (const float*)d_in[3];
  const float* bk = (const float*)d_in[4];
  const float* Wv = (const float*)d_in[5];
  const float* bv = (const float*)d_in[6];
  const float* Wo = (const float*)d_in[7];
  const float* bo = (const float*)d_in[8];
  const float* g1 = (const float*)d_in[9];
  const float* be1 = (const float*)d_in[10];
  const float* g2 = (const float*)d_in[11];
  const float* be2 = (const float*)d_in[12];
  const float* W1 = (const float*)d_in[13];
  const float* b1 = (const float*)d_in[14];
  const float* W2 = (const float*)d_in[15];
  const float* b2 = (const float*)d_in[16];
  float* out = (float*)d_out;

  char* ws = (char*)d_ws;
  float* x1 = (float*)ws;                                            // [0,16) MB fp32
  unsigned short* hbuf  = (unsigned short*)(ws + ((size_t)16 << 20)); // [16,24)
  unsigned short* qkvb  = (unsigned short*)(ws + ((size_t)24 << 20)); // [24,48)
  unsigned short* Ob    = (unsigned short*)(ws + ((size_t)48 << 20)); // [48,56)
  unsigned short* ff1   = (unsigned short*)(ws + ((size_t)24 << 20)); // [24,56) reuses qkv+Ob
  float* bqkv           = (float*)(ws + ((size_t)48 << 20));          // 12KB, dead before Ob
  unsigned short* WqkvT = (unsigned short*)(ws + ((size_t)56 << 20)); // [56,62)
  unsigned short* WoT   = (unsigned short*)(ws + ((size_t)62 << 20)); // [62,64)
  unsigned short* W1T   = (unsigned short*)(ws + ((size_t)64 << 20)); // [64,72)
  unsigned short* W2T   = (unsigned short*)(ws + ((size_t)72 << 20)); // [72,80)

  // weights + bias + LN1, one launch (LN1 independent of weight tiles)
  wcvt_all_kernel<<<dim3(4108), 256, 0, stream>>>(Wq, Wk, Wv, Wo, W1, W2, bq, bk, bv,
                                                  WqkvT, WoT, W1T, W2T, bqkv,
                                                  x, g1, be1, hbuf);

  gemm_bt4_kernel<0><<<dim3(24, 32), 256, 0, stream>>>(hbuf, WqkvT, bqkv, nullptr, qkvb,
                                                       4096, QKVW, 1024);
  (void)hipFuncSetAttribute((const void*)attn_kernel,
                            hipFuncAttributeMaxDynamicSharedMemorySize, ATTN_SMEM);
  attn_kernel<<<dim3(128, 16, 2), 1024, ATTN_SMEM, stream>>>(qkvb, Ob);
  gemm_n64_kernel<2><<<dim3(16, 32), 256, 0, stream>>>(Ob, WoT, bo, x, x1, 4096, 1024, 1024);
  ln_kernel<<<dim3(1024), 256, 0, stream>>>(x1, g2, be2, hbuf);
  gemm_bt4_kernel<1><<<dim3(32, 32), 256, 0, stream>>>(hbuf, W1T, b1, nullptr, ff1,
                                                       4096, 4096, 1024);
  gemm_n64_kernel<2><<<dim3(16, 32), 256, 0, stream>>>(ff1, W2T, b2, x1, out, 4096, 1024, 4096);
}